// Round 2
// 360.160 us; speedup vs baseline: 1.0671x; 1.0671x over previous
//
#include <hip/hip_runtime.h>
#include <math.h>

// ANI per-type MLP ensemble, MI355X bf16-MFMA.
// R6: R5 hardened. 2-wave blocks (128 thr), 64 atoms/block, wave w owns
//     M-tiles {2w, 2w+1} (32 atoms):
//       - each weight fragment loaded once per wave -> 2 MFMAs (R4: 1): L2
//         weight traffic 1.5GB -> 755MB, 2-way MFMA ILP per load
//       - AEV fragments global->reg direct (128B-coalesced via quad lanes),
//         1-deep prefetch, f32->bf16 packed RNE in-register; no X staging
//       - acc regs ~135/lane: no launch_bounds cap, no spills (R5: ~280 @ cap
//         256 -> spilled)
//       - full __syncthreads discipline around every H-store phase (wave row
//         regions overlap across strides: e.g. w1 H1-stores [8704,17408) hit
//         w0 H0-reads [0,10752))
//       - NO zpage (R5 risk removed): padded rows read aev row 0, energies
//         discarded by ai>=0 guard; ws footprint identical to proven R4
//       - layer 3 (96->1) via MFMA with w3 broadcast to all 16 B-cols
//     LDS: one arena H0(stride 168)->H1(136)->H2(104), 21504B -> 7 blocks/CU.

#define NATOMS   131072                     // 2048 * 64
#define NMOL     2048
#define AEV      384
#define NTYPES   4
#define MBLK     64                         // atoms per MLP block
#define PADTOT   (NATOMS + NTYPES * MBLK)   // 131328
#define NBLK_MLP (PADTOT / MBLK)            // 2052
#define NBLK_H   512                        // histogram blocks (256 atoms each)

// swizzled-weight layout (bf16, per type): L0 [12kt][10nt][64][8] = 61440,
// L1 [5][8][64][8] = 20480, L2 [4][6][64][8] = 12288  -> 94208 per type
#define WB_L1 61440
#define WB_L2 81920
#define WB_T  94208

typedef __attribute__((ext_vector_type(8))) short bf16x8;
typedef __attribute__((ext_vector_type(4))) float f32x4;

__device__ __forceinline__ float celu01(float v) {
  return (v > 0.f) ? v : 0.1f * (__expf(v * 10.f) - 1.f);  // v<0 => exp arg <0, safe
}
__device__ __forceinline__ unsigned short f2bf(float x) {  // RNE
  unsigned u = __float_as_uint(x);
  return (unsigned short)((u + 0x7FFFu + ((u >> 16) & 1u)) >> 16);
}
__device__ __forceinline__ unsigned int pk2(float lo, float hi) {  // 2x RNE packed
  unsigned a = __float_as_uint(lo), b = __float_as_uint(hi);
  a = (a + 0x7FFFu + ((a >> 16) & 1u)) >> 16;
  b = ((b + 0x7FFFu + ((b >> 16) & 1u)) >> 16) << 16;
  return a | b;
}

// ---- fused prep: out init + perm init + weight swizzle + histogram ----------

__global__ void k_pre(const int* __restrict__ species, float* __restrict__ out,
                      int* __restrict__ perm, int* __restrict__ hist,
                      const float* __restrict__ W0, const float* __restrict__ W1,
                      const float* __restrict__ W2, unsigned short* __restrict__ WB) {
  const int tid = threadIdx.x, blk = blockIdx.x;
  const int i = blk * 256 + tid;                  // grid = PADTOT/256 = 513
  perm[i] = -1;
  if (i < NATOMS) out[i] = (float)species[i];     // output 0: species passthrough
  if (i < NMOL) out[NATOMS + i] = 0.f;            // output 1: energies

  // weight swizzle, grid-stride over 4*WB_T elements
  for (int f = i; f < NTYPES * WB_T; f += PADTOT) {
    const int t = f / WB_T, e0 = f - t * WB_T;
    int base, NT, N;
    const float* W;
    if (e0 < WB_L1)      { base = 0;     NT = 10; N = 160; W = W0 + (size_t)t * AEV * 160; }
    else if (e0 < WB_L2) { base = WB_L1; NT = 8;  N = 128; W = W1 + (size_t)t * 160 * 128; }
    else                 { base = WB_L2; NT = 6;  N = 96;  W = W2 + (size_t)t * 128 * 96; }
    const int e = e0 - base, frag = e >> 9, r = e & 511, lane = r >> 3, j = r & 7;
    const int kt = frag / NT, nt = frag - kt * NT;
    const int k = kt * 32 + ((lane >> 4) << 3) + j, n = nt * 16 + (lane & 15);
    WB[(size_t)t * WB_T + e0] = f2bf(W[k * N + n]);
  }

  if (blk < NBLK_H) {                             // histogram (blocks 0..511)
    const int sp = species[i];
    const int wv = tid >> 6;
    __shared__ int wc[4 * NTYPES];
#pragma unroll
    for (int t = 0; t < NTYPES; ++t) {
      const unsigned long long m = __ballot(sp == t);
      if ((tid & 63) == 0) wc[wv * NTYPES + t] = __popcll(m);
    }
    __syncthreads();
    if (tid < NTYPES)
      hist[tid * NBLK_H + blk] = wc[tid] + wc[4 + tid] + wc[8 + tid] + wc[12 + tid];
  }
}

// ---- scan + scatter (atomic-free counting sort, unchanged) ------------------

__global__ void k_scan(const int* __restrict__ hist, int* __restrict__ poff,
                       int* __restrict__ boff) {
  __shared__ int tot[NTYPES], base[NTYPES];
  const int tid = threadIdx.x, wv = tid >> 6, lane = tid & 63;
  int s = 0;
  for (int c = 0; c < 8; ++c) s += hist[wv * NBLK_H + c * 64 + lane];
  for (int off = 32; off; off >>= 1) s += __shfl_down(s, off);
  if (lane == 0) tot[wv] = s;
  __syncthreads();
  if (tid == 0) {
    int acc = 0; poff[0] = 0;
    for (int t = 0; t < NTYPES; ++t) {
      base[t] = acc;
      acc += ((tot[t] + 63) >> 6) << 6;
      poff[t + 1] = acc;
    }
  }
  __syncthreads();
  int carry = base[wv];
  for (int c = 0; c < 8; ++c) {
    const int orig = hist[wv * NBLK_H + c * 64 + lane];
    int v = orig;
    for (int off = 1; off < 64; off <<= 1) {
      const int u = __shfl_up(v, off);
      if (lane >= off) v += u;
    }
    boff[wv * NBLK_H + c * 64 + lane] = carry + v - orig;
    carry += __shfl(v, 63);
  }
}

__global__ void k_scatter(const int* __restrict__ species, const int* __restrict__ boff,
                          int* __restrict__ perm) {
  const int tid = threadIdx.x, blk = blockIdx.x;
  const int i = blk * 256 + tid;
  const int sp = species[i];
  const int wv = tid >> 6;
  __shared__ int wc[4 * NTYPES];
  unsigned long long msel = 0;
#pragma unroll
  for (int t = 0; t < NTYPES; ++t) {
    const unsigned long long m = __ballot(sp == t);
    if ((tid & 63) == 0) wc[wv * NTYPES + t] = __popcll(m);
    if (sp == t) msel = m;
  }
  __syncthreads();
  int woff = 0;
  for (int w = 0; w < wv; ++w) woff += wc[w * NTYPES + sp];
  const int rk = __builtin_amdgcn_mbcnt_hi((unsigned)(msel >> 32),
                 __builtin_amdgcn_mbcnt_lo((unsigned)msel, 0));
  perm[boff[sp * NBLK_H + blk] + woff + rk] = i;
}

// ---- 2-wave fused 4-layer MFMA MLP + molecule reduction ---------------------
// 128 threads = 2 waves; wave w owns M-tiles {2w, 2w+1} = rows [32w, 32w+32).
// A-fragments (M=16,K=32 bf16): lane holds row l&15, k = (l>>4)*8 + j, so lanes
// {x,x+16,x+32,x+48} cover one contiguous 128B line of an aev row -> coalesced
// direct global->reg loads, converted f32->bf16 in-register (packed RNE).

__global__ __launch_bounds__(128) void k_mlp(
    const float* __restrict__ aev, const unsigned short* __restrict__ WB,
    const float* __restrict__ b0, const float* __restrict__ b1,
    const float* __restrict__ b2, const float* __restrict__ b3,
    const float* __restrict__ W3,
    const int* __restrict__ poff, const int* __restrict__ perm,
    float* __restrict__ outE)
{
  __shared__ __align__(16) unsigned short H[64 * 168];   // 21504 B
  __shared__ int permS[64];

  const int tid  = threadIdx.x;
  const int lane = tid & 63;
  const int wv   = __builtin_amdgcn_readfirstlane(tid >> 6);   // 0 / 1
  const int quad = lane >> 4, l15 = lane & 15;
  const int slot0 = blockIdx.x * MBLK;

  if (tid < 64) permS[tid] = perm[slot0 + tid];
  int t_ = (slot0 >= poff[1]) + (slot0 >= poff[2]) + (slot0 >= poff[3]);
  if (t_ > 3) t_ = 3;
  const int t = __builtin_amdgcn_readfirstlane(t_);
  __syncthreads();

  // per-M-tile row pointers (padded rows -> aev row 0; results discarded)
  const float* rp[2];
#pragma unroll
  for (int mtl = 0; mtl < 2; ++mtl) {
    const int ai = permS[(2 * wv + mtl) * 16 + l15];
    rp[mtl] = aev + (size_t)(ai < 0 ? 0 : ai) * AEV + quad * 8;
  }

  const bf16x8* wb0 = (const bf16x8*)(WB + (size_t)t * WB_T);
  const bf16x8* wb1 = (const bf16x8*)(WB + (size_t)t * WB_T + WB_L1);
  const bf16x8* wb2 = (const bf16x8*)(WB + (size_t)t * WB_T + WB_L2);

  union U8 { unsigned int u[4]; bf16x8 v; };

  // ---------------- layer 0: 384 -> 160 --------------------------------------
  f32x4 acc0[10][2];
#pragma unroll
  for (int nt = 0; nt < 10; ++nt) {
    const float b = b0[t * 160 + nt * 16 + l15];
#pragma unroll
    for (int mtl = 0; mtl < 2; ++mtl) acc0[nt][mtl] = (f32x4){b, b, b, b};
  }

  float4 raw[2][2];
#pragma unroll
  for (int mtl = 0; mtl < 2; ++mtl) {                    // prologue: ks = 0
    raw[mtl][0] = *(const float4*)(rp[mtl]);
    raw[mtl][1] = *(const float4*)(rp[mtl] + 4);
  }

  for (int ks = 0; ks < 12; ++ks) {
    bf16x8 a[2];
#pragma unroll
    for (int mtl = 0; mtl < 2; ++mtl) {                  // convert current
      U8 c;
      c.u[0] = pk2(raw[mtl][0].x, raw[mtl][0].y);
      c.u[1] = pk2(raw[mtl][0].z, raw[mtl][0].w);
      c.u[2] = pk2(raw[mtl][1].x, raw[mtl][1].y);
      c.u[3] = pk2(raw[mtl][1].z, raw[mtl][1].w);
      a[mtl] = c.v;
    }
    if (ks < 11) {                                       // prefetch next K-slice
#pragma unroll
      for (int mtl = 0; mtl < 2; ++mtl) {
        const float* p = rp[mtl] + (ks + 1) * 32;
        raw[mtl][0] = *(const float4*)p;
        raw[mtl][1] = *(const float4*)(p + 4);
      }
    }
#pragma unroll
    for (int nt = 0; nt < 10; ++nt) {
      const bf16x8 w = wb0[(ks * 10 + nt) * 64 + lane];  // one load -> 2 MFMAs
#pragma unroll
      for (int mtl = 0; mtl < 2; ++mtl)
        acc0[nt][mtl] = __builtin_amdgcn_mfma_f32_16x16x32_bf16(a[mtl], w, acc0[nt][mtl], 0, 0, 0);
    }
  }
#pragma unroll
  for (int nt = 0; nt < 10; ++nt)                        // H0: stride 168
#pragma unroll
    for (int mtl = 0; mtl < 2; ++mtl)
#pragma unroll
      for (int r = 0; r < 4; ++r)
        H[((2 * wv + mtl) * 16 + quad * 4 + r) * 168 + nt * 16 + l15] = f2bf(celu01(acc0[nt][mtl][r]));
  __syncthreads();                                       // H0 visible / fence

  // ---------------- layer 1: 160 -> 128 --------------------------------------
  f32x4 acc1[8][2];
#pragma unroll
  for (int nt = 0; nt < 8; ++nt) {
    const float b = b1[t * 128 + nt * 16 + l15];
#pragma unroll
    for (int mtl = 0; mtl < 2; ++mtl) acc1[nt][mtl] = (f32x4){b, b, b, b};
  }
#pragma unroll
  for (int ks = 0; ks < 5; ++ks) {
    bf16x8 a[2];
#pragma unroll
    for (int mtl = 0; mtl < 2; ++mtl)
      a[mtl] = *(const bf16x8*)&H[((2 * wv + mtl) * 16 + l15) * 168 + quad * 8 + ks * 32];
#pragma unroll
    for (int nt = 0; nt < 8; ++nt) {
      const bf16x8 w = wb1[(ks * 8 + nt) * 64 + lane];
#pragma unroll
      for (int mtl = 0; mtl < 2; ++mtl)
        acc1[nt][mtl] = __builtin_amdgcn_mfma_f32_16x16x32_bf16(a[mtl], w, acc1[nt][mtl], 0, 0, 0);
    }
  }
  __syncthreads();                                       // all H0 reads done
#pragma unroll
  for (int nt = 0; nt < 8; ++nt)                         // H1: stride 136
#pragma unroll
    for (int mtl = 0; mtl < 2; ++mtl)
#pragma unroll
      for (int r = 0; r < 4; ++r)
        H[((2 * wv + mtl) * 16 + quad * 4 + r) * 136 + nt * 16 + l15] = f2bf(celu01(acc1[nt][mtl][r]));
  __syncthreads();                                       // H1 visible / fence

  // ---------------- layer 2: 128 -> 96 ---------------------------------------
  f32x4 acc2[6][2];
#pragma unroll
  for (int nt = 0; nt < 6; ++nt) {
    const float b = b2[t * 96 + nt * 16 + l15];
#pragma unroll
    for (int mtl = 0; mtl < 2; ++mtl) acc2[nt][mtl] = (f32x4){b, b, b, b};
  }
#pragma unroll
  for (int ks = 0; ks < 4; ++ks) {
    bf16x8 a[2];
#pragma unroll
    for (int mtl = 0; mtl < 2; ++mtl)
      a[mtl] = *(const bf16x8*)&H[((2 * wv + mtl) * 16 + l15) * 136 + quad * 8 + ks * 32];
#pragma unroll
    for (int nt = 0; nt < 6; ++nt) {
      const bf16x8 w = wb2[(ks * 6 + nt) * 64 + lane];
#pragma unroll
      for (int mtl = 0; mtl < 2; ++mtl)
        acc2[nt][mtl] = __builtin_amdgcn_mfma_f32_16x16x32_bf16(a[mtl], w, acc2[nt][mtl], 0, 0, 0);
    }
  }
  __syncthreads();                                       // all H1 reads done
#pragma unroll
  for (int nt = 0; nt < 6; ++nt)                         // H2: stride 104
#pragma unroll
    for (int mtl = 0; mtl < 2; ++mtl)
#pragma unroll
      for (int r = 0; r < 4; ++r)
        H[((2 * wv + mtl) * 16 + quad * 4 + r) * 104 + nt * 16 + l15] = f2bf(celu01(acc2[nt][mtl][r]));
  __syncthreads();                                       // H2 visible / fence

  // ---------------- layer 3: 96 -> 1 via MFMA (w3 broadcast to all 16 cols) --
  bf16x8 w3f[3];
#pragma unroll
  for (int ks = 0; ks < 3; ++ks) {
    const float* wp = W3 + t * 96 + ks * 32 + quad * 8;  // uniform across l15
    const float4 f0 = *(const float4*)wp;
    const float4 f1 = *(const float4*)(wp + 4);
    U8 c;
    c.u[0] = pk2(f0.x, f0.y);
    c.u[1] = pk2(f0.z, f0.w);
    c.u[2] = pk2(f1.x, f1.y);
    c.u[3] = pk2(f1.z, f1.w);
    w3f[ks] = c.v;
  }
  f32x4 accE[2];
#pragma unroll
  for (int mtl = 0; mtl < 2; ++mtl) accE[mtl] = (f32x4){0.f, 0.f, 0.f, 0.f};
#pragma unroll
  for (int mtl = 0; mtl < 2; ++mtl)
#pragma unroll
    for (int ks = 0; ks < 3; ++ks) {
      const bf16x8 a = *(const bf16x8*)&H[((2 * wv + mtl) * 16 + l15) * 104 + quad * 8 + ks * 32];
      accE[mtl] = __builtin_amdgcn_mfma_f32_16x16x32_bf16(a, w3f[ks], accE[mtl], 0, 0, 0);
    }
  // accE[mtl][r] = energy of atom (2wv+mtl)*16 + quad*4 + r, identical over l15
  const float bb3 = b3[t];
#pragma unroll
  for (int mtl = 0; mtl < 2; ++mtl)
#pragma unroll
    for (int r = 0; r < 4; ++r)
      if (l15 == 0) {
        const int ai = permS[(2 * wv + mtl) * 16 + quad * 4 + r];
        if (ai >= 0) atomicAdd(&outE[ai >> 6], accE[mtl][r] + bb3);
      }
}

// ---- launch -----------------------------------------------------------------

extern "C" void kernel_launch(void* const* d_in, const int* in_sizes, int n_in,
                              void* d_out, int out_size, void* d_ws, size_t ws_size,
                              hipStream_t stream)
{
  const int*   species = (const int*)d_in[0];
  const float* aev     = (const float*)d_in[1];
  const float* W0 = (const float*)d_in[2];
  const float* b0 = (const float*)d_in[3];
  const float* W1 = (const float*)d_in[4];
  const float* b1 = (const float*)d_in[5];
  const float* W2 = (const float*)d_in[6];
  const float* b2 = (const float*)d_in[7];
  const float* W3 = (const float*)d_in[8];
  const float* b3 = (const float*)d_in[9];
  float* out = (float*)d_out;

  // ws (ints): poff[8], hist[2048], boff[2048], perm[PADTOT]; then bf16 WB
  int* poff = (int*)d_ws;
  int* hist = poff + 8;
  int* boff = hist + NTYPES * NBLK_H;
  int* perm = boff + NTYPES * NBLK_H;
  unsigned short* WB = (unsigned short*)(perm + PADTOT);

  k_pre    <<<PADTOT / 256, 256, 0, stream>>>(species, out, perm, hist, W0, W1, W2, WB);
  k_scan   <<<1, 256, 0, stream>>>(hist, poff, boff);
  k_scatter<<<NBLK_H, 256, 0, stream>>>(species, boff, perm);
  k_mlp    <<<NBLK_MLP, 128, 0, stream>>>(aev, WB, b0, b1, b2, b3, W3,
                                          poff, perm, out + NATOMS);
}